// Round 1
// baseline (257.395 us; speedup 1.0000x reference)
//
#include <hip/hip_runtime.h>
#include <math.h>

// ExodusNeuron: per-(b,n) sequential scan over T with spike threshold/reset.
// x: (B=32, T=2048, N=512, 1) fp32; weight: (1,1) fp32; out: (B,T,N,1) fp32.
//
// One thread per (b,n) sequence: 16384 threads = 256 waves = 1 wave/CU.
// Coalescing: at each t, a wave (64 consecutive n) touches 256B contiguous.
// Latency hiding via register double-buffering of D=32 time steps.
//
// Numerics MUST match numpy's fp32 rounding exactly (outputs are 0/1 spikes;
// a flipped spike = absmax 1.0): separate rounded mul/add (no FMA), and
// alpha = correctly-rounded float of exp(double(float(-0.05))).

constexpr int B_ = 32;
constexpr int T_ = 2048;
constexpr int N_ = 512;
constexpr int D_ = 32;            // prefetch batch depth (time steps)
constexpr int NBATCH = T_ / D_;   // 64 batches

__global__ __launch_bounds__(64)
void exodus_neuron_kernel(const float* __restrict__ x,
                          const float* __restrict__ wptr,
                          float* __restrict__ out) {
    const int tid = blockIdx.x * 64 + threadIdx.x;   // 0..16383
    const int b = tid >> 9;                          // tid / 512
    const int n = tid & (N_ - 1);                    // tid % 512
    const float w = wptr[0];
    // exp(-1/20) rounded exactly as numpy float32 does it:
    const float alpha = (float)exp((double)(-1.0f / 20.0f));

    const int base = b * (T_ * N_) + n;
    const float* __restrict__ xp = x + base;
    float* __restrict__ op = out + base;

    float vsyn = 0.0f;
    float vmem = 0.0f;
    float bufA[D_], bufB[D_];

    // preload batch 0 into A
#pragma unroll
    for (int j = 0; j < D_; ++j)
        bufA[j] = xp[j * N_];

    for (int k = 0; k < NBATCH; k += 2) {
        // prefetch batch k+1 into B (always exists: NBATCH even)
        {
            const float* __restrict__ p = xp + (k + 1) * (D_ * N_);
#pragma unroll
            for (int j = 0; j < D_; ++j)
                bufB[j] = p[j * N_];
        }
        // compute batch k from A
        {
            float* __restrict__ o = op + k * (D_ * N_);
#pragma unroll
            for (int j = 0; j < D_; ++j) {
                const float i_t = __fmul_rn(bufA[j], w);
                vsyn = __fadd_rn(__fmul_rn(alpha, vsyn), i_t);
                vmem = __fadd_rn(__fmul_rn(alpha, vmem), vsyn);
                const float spk = (vmem >= 1.0f) ? 1.0f : 0.0f;
                o[j * N_] = spk;
                vmem = __fsub_rn(vmem, spk);
            }
        }
        // prefetch batch k+2 into A
        if (k + 2 < NBATCH) {
            const float* __restrict__ p = xp + (k + 2) * (D_ * N_);
#pragma unroll
            for (int j = 0; j < D_; ++j)
                bufA[j] = p[j * N_];
        }
        // compute batch k+1 from B
        {
            float* __restrict__ o = op + (k + 1) * (D_ * N_);
#pragma unroll
            for (int j = 0; j < D_; ++j) {
                const float i_t = __fmul_rn(bufB[j], w);
                vsyn = __fadd_rn(__fmul_rn(alpha, vsyn), i_t);
                vmem = __fadd_rn(__fmul_rn(alpha, vmem), vsyn);
                const float spk = (vmem >= 1.0f) ? 1.0f : 0.0f;
                o[j * N_] = spk;
                vmem = __fsub_rn(vmem, spk);
            }
        }
    }
}

extern "C" void kernel_launch(void* const* d_in, const int* in_sizes, int n_in,
                              void* d_out, int out_size, void* d_ws, size_t ws_size,
                              hipStream_t stream) {
    const float* x = (const float*)d_in[0];
    const float* w = (const float*)d_in[1];
    float* out = (float*)d_out;

    const int total_threads = B_ * N_;   // 16384
    dim3 grid(total_threads / 64);       // 256 blocks -> 1 wave per CU
    dim3 block(64);
    hipLaunchKernelGGL(exodus_neuron_kernel, grid, block, 0, stream,
                       x, w, out);
}